// Round 5
// baseline (392.570 us; speedup 1.0000x reference)
//
#include <hip/hip_runtime.h>

#define N_NODES 100000
#define N_EDGES 1600000
#define NBUCK 196   // ceil(N_NODES / 512)
#define EPB 4096    // edges per block in bucket_scatter
#define CAPB 9500   // LDS staging capacity in bucket_sort (mean 8192, sigma ~90)

static constexpr float BN_EPS = 1e-5f;
static constexpr float SLOPE = 0.3f;

__device__ __forceinline__ float bf16_to_f32(ushort u) {
  return __uint_as_float((unsigned)u << 16);
}
__device__ __forceinline__ ushort f32_to_bf16(float f) {
  unsigned bits = __float_as_uint(f);
  bits += 0x7FFFu + ((bits >> 16) & 1u);  // round-to-nearest-even
  return (ushort)(bits >> 16);
}

// ---------------------------------------------------------------------------
// Pass 1: per-node transforms.
//   A[n] = feat[n] @ (W1 - W2)^T + b   (fp32, stored in d_out)
//   B[n] = feat[n] @ W2^T              (bf16 gather pool, 12.8 MB)
// lane = output channel; weight column register-resident (128 VGPR);
// feat row read as wave-uniform float4 (one line, HW broadcast). No LDS.
// ---------------------------------------------------------------------------
__global__ __launch_bounds__(256) void node_transform_kernel(
    const float* __restrict__ feat, const float* __restrict__ W,
    const float* __restrict__ bias, float* __restrict__ A,
    ushort* __restrict__ Bmh) {
  int lane = threadIdx.x & 63;
  int wv = threadIdx.x >> 6;

  float wa[64], wb[64];
#pragma unroll
  for (int q = 0; q < 16; ++q) {  // per-lane contiguous 256B+256B
    float4 w1 = *(const float4*)&W[lane * 128 + q * 4];
    float4 w2 = *(const float4*)&W[lane * 128 + 64 + q * 4];
    wa[q * 4 + 0] = w1.x - w2.x;
    wa[q * 4 + 1] = w1.y - w2.y;
    wa[q * 4 + 2] = w1.z - w2.z;
    wa[q * 4 + 3] = w1.w - w2.w;
    wb[q * 4 + 0] = w2.x;
    wb[q * 4 + 1] = w2.y;
    wb[q * 4 + 2] = w2.z;
    wb[q * 4 + 3] = w2.w;
  }
  float bc = bias[lane];

  int gwave = blockIdx.x * 4 + wv;
  int nwaves = gridDim.x * 4;
  int chunk = (N_NODES + nwaves - 1) / nwaves;
  int n0 = gwave * chunk;
  int n1 = min(n0 + chunk, N_NODES);

  for (int n = n0; n < n1; ++n) {  // sequential rows -> streaming reads
    const float4* fr = (const float4*)(feat + (size_t)n * 64);
    float a = bc, bs = 0.f;
#pragma unroll
    for (int qq = 0; qq < 4; ++qq) {  // 4 float4 loads in flight per group
      float4 f0 = fr[qq * 4 + 0];
      float4 f1 = fr[qq * 4 + 1];
      float4 f2 = fr[qq * 4 + 2];
      float4 f3 = fr[qq * 4 + 3];
      int k = qq * 16;
      a = fmaf(f0.x, wa[k + 0], a);   bs = fmaf(f0.x, wb[k + 0], bs);
      a = fmaf(f0.y, wa[k + 1], a);   bs = fmaf(f0.y, wb[k + 1], bs);
      a = fmaf(f0.z, wa[k + 2], a);   bs = fmaf(f0.z, wb[k + 2], bs);
      a = fmaf(f0.w, wa[k + 3], a);   bs = fmaf(f0.w, wb[k + 3], bs);
      a = fmaf(f1.x, wa[k + 4], a);   bs = fmaf(f1.x, wb[k + 4], bs);
      a = fmaf(f1.y, wa[k + 5], a);   bs = fmaf(f1.y, wb[k + 5], bs);
      a = fmaf(f1.z, wa[k + 6], a);   bs = fmaf(f1.z, wb[k + 6], bs);
      a = fmaf(f1.w, wa[k + 7], a);   bs = fmaf(f1.w, wb[k + 7], bs);
      a = fmaf(f2.x, wa[k + 8], a);   bs = fmaf(f2.x, wb[k + 8], bs);
      a = fmaf(f2.y, wa[k + 9], a);   bs = fmaf(f2.y, wb[k + 9], bs);
      a = fmaf(f2.z, wa[k + 10], a);  bs = fmaf(f2.z, wb[k + 10], bs);
      a = fmaf(f2.w, wa[k + 11], a);  bs = fmaf(f2.w, wb[k + 11], bs);
      a = fmaf(f3.x, wa[k + 12], a);  bs = fmaf(f3.x, wb[k + 12], bs);
      a = fmaf(f3.y, wa[k + 13], a);  bs = fmaf(f3.y, wb[k + 13], bs);
      a = fmaf(f3.z, wa[k + 14], a);  bs = fmaf(f3.z, wb[k + 14], bs);
      a = fmaf(f3.w, wa[k + 15], a);  bs = fmaf(f3.w, wb[k + 15], bs);
    }
    A[(size_t)n * 64 + lane] = a;
    Bmh[(size_t)n * 64 + lane] = f32_to_bf16(bs);
  }
}

// ---------------------------------------------------------------------------
// CSR build: degree histogram -> 3-dispatch parallel scan.
// ---------------------------------------------------------------------------
__global__ __launch_bounds__(256) void degree_kernel(const int* __restrict__ ei,
                                                     int* __restrict__ deg) {
  int e = blockIdx.x * 256 + threadIdx.x;
  if (e < N_EDGES) atomicAdd(&deg[ei[N_EDGES + e]], 1);  // dst
}

__global__ __launch_bounds__(1024) void scan1_kernel(const int* __restrict__ deg,
                                                     int* __restrict__ pre,
                                                     int* __restrict__ bsum) {
  __shared__ int sh[1024];
  int t = threadIdx.x;
  int i = blockIdx.x * 1024 + t;
  int v = (i < N_NODES) ? deg[i] : 0;
  sh[t] = v;
  __syncthreads();
  for (int off = 1; off < 1024; off <<= 1) {
    int u = (t >= off) ? sh[t - off] : 0;
    __syncthreads();
    sh[t] += u;
    __syncthreads();
  }
  if (i < N_NODES) pre[i] = sh[t] - v;  // exclusive within block
  if (t == 1023) bsum[blockIdx.x] = sh[1023];
}

__global__ __launch_bounds__(128) void scan2_kernel(int* __restrict__ bsum,
                                                    int nb) {
  __shared__ int sh[128];
  int t = threadIdx.x;
  int v = (t < nb) ? bsum[t] : 0;
  sh[t] = v;
  __syncthreads();
  for (int off = 1; off < 128; off <<= 1) {
    int u = (t >= off) ? sh[t - off] : 0;
    __syncthreads();
    sh[t] += u;
    __syncthreads();
  }
  if (t < nb) bsum[t] = sh[t] - v;  // exclusive
}

__global__ __launch_bounds__(256) void scan3_kernel(const int* __restrict__ pre,
                                                    const int* __restrict__ bsum,
                                                    int* __restrict__ row_ptr,
                                                    int* __restrict__ gcur) {
  int i = blockIdx.x * 256 + threadIdx.x;
  if (i < N_NODES) {
    int r = pre[i] + bsum[i >> 10];
    row_ptr[i] = r;
    if ((i & 511) == 0) gcur[i >> 9] = r;  // bucket base cursor
  }
  if (i == 0) row_ptr[N_NODES] = N_EDGES;
}

// ---------------------------------------------------------------------------
// B1: coarse bucket scatter (block-aggregated reservation, packed u32 runs).
// ---------------------------------------------------------------------------
__global__ __launch_bounds__(256) void bucket_scatter_kernel(
    const int* __restrict__ ei, int* __restrict__ gcur,
    unsigned* __restrict__ pbuf) {
  __shared__ int base[NBUCK];
  __shared__ int hist[NBUCK];
  int t = threadIdx.x;
  int e0 = blockIdx.x * EPB;
  int nE = min(EPB, N_EDGES - e0);

  for (int i = t; i < NBUCK; i += 256) hist[i] = 0;
  __syncthreads();
  for (int i = t; i < nE; i += 256) {
    int d = ei[N_EDGES + e0 + i];
    atomicAdd(&hist[d >> 9], 1);
  }
  __syncthreads();
  for (int i = t; i < NBUCK; i += 256) {
    int h = hist[i];
    base[i] = h ? atomicAdd(&gcur[i], h) : 0;
    hist[i] = 0;  // reuse as local cursor
  }
  __syncthreads();
  for (int i = t; i < nE; i += 256) {
    int d = ei[N_EDGES + e0 + i];
    int s = ei[e0 + i];
    int b = d >> 9;
    int off = atomicAdd(&hist[b], 1);
    pbuf[base[b] + off] = ((unsigned)(d & 511) << 17) | (unsigned)s;
  }
}

// ---------------------------------------------------------------------------
// B2: per-bucket fine sort via LDS staging.
// ---------------------------------------------------------------------------
__global__ __launch_bounds__(1024) void bucket_sort_kernel(
    const int* __restrict__ row_ptr, const unsigned* __restrict__ pbuf,
    int* __restrict__ esrc) {
  __shared__ int pref[512];
  __shared__ int cur[512];
  __shared__ int buf[CAPB];
  int t = threadIdx.x;
  int node0 = blockIdx.x << 9;
  int nn = min(512, N_NODES - node0);
  int fbase = row_ptr[node0];
  int fend = row_ptr[min(node0 + 512, N_NODES)];
  int m = fend - fbase;
  if (t < nn) {
    pref[t] = row_ptr[node0 + t] - fbase;
    cur[t] = 0;
  }
  __syncthreads();
  for (int i = t; i < m; i += 1024) {
    unsigned v = pbuf[fbase + i];
    int ldst = v >> 17;
    int src = (int)(v & 0x1FFFFu);
    int pos = pref[ldst] + atomicAdd(&cur[ldst], 1);
    if (pos < CAPB) buf[pos] = src;
    else esrc[fbase + pos] = src;  // overflow fallback (statistically never)
  }
  __syncthreads();
  int lim = min(m, CAPB);
  for (int i = t; i < lim; i += 1024) esrc[fbase + i] = buf[i];
}

// ---------------------------------------------------------------------------
// Pass 2: BN statistics, pull-based. bf16 gathers, 8-deep pipelined.
// ---------------------------------------------------------------------------
__global__ __launch_bounds__(256) void stats_kernel(
    const int* __restrict__ row_ptr, const int* __restrict__ esrc,
    const float* __restrict__ A, const ushort* __restrict__ Bmh,
    float* __restrict__ sums) {
  int lane = threadIdx.x & 63;
  int wv = threadIdx.x >> 6;
  int gwave = blockIdx.x * 4 + wv;
  int nwaves = gridDim.x * 4;

  float s = 0.f, sq = 0.f;
  for (int n = gwave; n < N_NODES; n += nwaves) {
    float a = A[n * 64 + lane];
    int lo = row_ptr[n], hi = row_ptr[n + 1];
    for (int base = lo; base < hi; base += 64) {
      int nb = min(64, hi - base);
      int sidx = (lane < nb) ? esrc[base + lane] : 0;  // coalesced
      int k = 0;
      for (; k + 8 <= nb; k += 8) {
        int i0 = __shfl(sidx, k + 0), i1 = __shfl(sidx, k + 1);
        int i2 = __shfl(sidx, k + 2), i3 = __shfl(sidx, k + 3);
        int i4 = __shfl(sidx, k + 4), i5 = __shfl(sidx, k + 5);
        int i6 = __shfl(sidx, k + 6), i7 = __shfl(sidx, k + 7);
        ushort u0 = Bmh[i0 * 64 + lane];  // 8 independent gathers in flight
        ushort u1 = Bmh[i1 * 64 + lane];
        ushort u2 = Bmh[i2 * 64 + lane];
        ushort u3 = Bmh[i3 * 64 + lane];
        ushort u4 = Bmh[i4 * 64 + lane];
        ushort u5 = Bmh[i5 * 64 + lane];
        ushort u6 = Bmh[i6 * 64 + lane];
        ushort u7 = Bmh[i7 * 64 + lane];
        float m0 = a + bf16_to_f32(u0), m1 = a + bf16_to_f32(u1);
        float m2 = a + bf16_to_f32(u2), m3 = a + bf16_to_f32(u3);
        float m4 = a + bf16_to_f32(u4), m5 = a + bf16_to_f32(u5);
        float m6 = a + bf16_to_f32(u6), m7 = a + bf16_to_f32(u7);
        s += ((m0 + m1) + (m2 + m3)) + ((m4 + m5) + (m6 + m7));
        sq = fmaf(m0, m0, sq); sq = fmaf(m1, m1, sq);
        sq = fmaf(m2, m2, sq); sq = fmaf(m3, m3, sq);
        sq = fmaf(m4, m4, sq); sq = fmaf(m5, m5, sq);
        sq = fmaf(m6, m6, sq); sq = fmaf(m7, m7, sq);
      }
      for (; k < nb; ++k) {
        int i0 = __shfl(sidx, k);
        float m = a + bf16_to_f32(Bmh[i0 * 64 + lane]);
        s += m;
        sq = fmaf(m, m, sq);
      }
    }
  }
  __shared__ float ls[4][64];
  __shared__ float lq[4][64];
  ls[wv][lane] = s;
  lq[wv][lane] = sq;
  __syncthreads();
  if (wv == 0) {
    atomicAdd(&sums[lane], ls[0][lane] + ls[1][lane] + ls[2][lane] + ls[3][lane]);
    atomicAdd(&sums[64 + lane],
              lq[0][lane] + lq[1][lane] + lq[2][lane] + lq[3][lane]);
  }
}

__global__ __launch_bounds__(64) void bn_params_kernel(
    const float* __restrict__ sums, const float* __restrict__ gamma,
    const float* __restrict__ beta, float* __restrict__ ss) {
  int c = threadIdx.x;
  const float invE = 1.0f / (float)N_EDGES;
  float mu = sums[c] * invE;
  float var = sums[64 + c] * invE - mu * mu;
  float rs = rsqrtf(var + BN_EPS);
  float sc = gamma[c] * rs;
  ss[c] = sc;
  ss[64 + c] = beta[c] - mu * sc;
}

// ---------------------------------------------------------------------------
// Pass 3: aggregation, pull-based, bf16 gathers, 8-deep pipelined.
// ---------------------------------------------------------------------------
__global__ __launch_bounds__(256) void aggregate_kernel(
    const int* __restrict__ row_ptr, const int* __restrict__ esrc,
    const float* __restrict__ A, const ushort* __restrict__ Bmh,
    const float* __restrict__ ss, float* __restrict__ out) {
  int lane = threadIdx.x & 63;
  int wv = threadIdx.x >> 6;
  int gwave = blockIdx.x * 4 + wv;
  int nwaves = gridDim.x * 4;

  float sc = ss[lane];
  float sh = ss[64 + lane];

  for (int n = gwave; n < N_NODES; n += nwaves) {
    float a = A[n * 64 + lane];  // A aliases out: read before write
    int lo = row_ptr[n], hi = row_ptr[n + 1];
    float acc = 0.f;
    for (int base = lo; base < hi; base += 64) {
      int nb = min(64, hi - base);
      int sidx = (lane < nb) ? esrc[base + lane] : 0;
      int k = 0;
      for (; k + 8 <= nb; k += 8) {
        int i0 = __shfl(sidx, k + 0), i1 = __shfl(sidx, k + 1);
        int i2 = __shfl(sidx, k + 2), i3 = __shfl(sidx, k + 3);
        int i4 = __shfl(sidx, k + 4), i5 = __shfl(sidx, k + 5);
        int i6 = __shfl(sidx, k + 6), i7 = __shfl(sidx, k + 7);
        ushort u0 = Bmh[i0 * 64 + lane];
        ushort u1 = Bmh[i1 * 64 + lane];
        ushort u2 = Bmh[i2 * 64 + lane];
        ushort u3 = Bmh[i3 * 64 + lane];
        ushort u4 = Bmh[i4 * 64 + lane];
        ushort u5 = Bmh[i5 * 64 + lane];
        ushort u6 = Bmh[i6 * 64 + lane];
        ushort u7 = Bmh[i7 * 64 + lane];
        float y0 = fmaf(a + bf16_to_f32(u0), sc, sh);
        float y1 = fmaf(a + bf16_to_f32(u1), sc, sh);
        float y2 = fmaf(a + bf16_to_f32(u2), sc, sh);
        float y3 = fmaf(a + bf16_to_f32(u3), sc, sh);
        float y4 = fmaf(a + bf16_to_f32(u4), sc, sh);
        float y5 = fmaf(a + bf16_to_f32(u5), sc, sh);
        float y6 = fmaf(a + bf16_to_f32(u6), sc, sh);
        float y7 = fmaf(a + bf16_to_f32(u7), sc, sh);
        y0 = (y0 >= 0.f) ? y0 : SLOPE * y0;
        y1 = (y1 >= 0.f) ? y1 : SLOPE * y1;
        y2 = (y2 >= 0.f) ? y2 : SLOPE * y2;
        y3 = (y3 >= 0.f) ? y3 : SLOPE * y3;
        y4 = (y4 >= 0.f) ? y4 : SLOPE * y4;
        y5 = (y5 >= 0.f) ? y5 : SLOPE * y5;
        y6 = (y6 >= 0.f) ? y6 : SLOPE * y6;
        y7 = (y7 >= 0.f) ? y7 : SLOPE * y7;
        acc += ((y0 + y1) + (y2 + y3)) + ((y4 + y5) + (y6 + y7));
      }
      for (; k < nb; ++k) {
        int i0 = __shfl(sidx, k);
        float y = fmaf(a + bf16_to_f32(Bmh[i0 * 64 + lane]), sc, sh);
        acc += (y >= 0.f) ? y : SLOPE * y;
      }
    }
    int cnt = hi - lo;
    out[n * 64 + lane] = acc * (1.0f / (float)max(cnt, 1));
  }
}

extern "C" void kernel_launch(void* const* d_in, const int* in_sizes, int n_in,
                              void* d_out, int out_size, void* d_ws,
                              size_t ws_size, hipStream_t stream) {
  const float* feat = (const float*)d_in[0];
  const int* ei = (const int*)d_in[1];
  const float* W = (const float*)d_in[2];
  const float* b = (const float*)d_in[3];
  const float* gamma = (const float*)d_in[4];
  const float* beta = (const float*)d_in[5];
  float* out = (float*)d_out;

  float* A = out;  // A lives in d_out; final pass overwrites in place

  // Workspace layout (~27 MB)
  ushort* Bmh = (ushort*)d_ws;                        // N*64 bf16 (12.8 MB)
  float* sums = (float*)(Bmh + (size_t)N_NODES * 64); // 128 f
  float* ss = sums + 128;                             // 128 f
  int* deg = (int*)(ss + 128);                        // N
  int* row_ptr = deg + N_NODES;                       // N+1
  int* pre = row_ptr + N_NODES + 1;                   // N
  int* bsum = pre + N_NODES;                          // 128
  int* gcur = bsum + 128;                             // NBUCK
  unsigned* pbuf = (unsigned*)(gcur + NBUCK);         // E packed
  int* esrc = (int*)(pbuf + N_EDGES);                 // E

  const int NB_SCAN = (N_NODES + 1023) / 1024;  // 98

  hipMemsetAsync(deg, 0, (size_t)N_NODES * sizeof(int), stream);
  hipMemsetAsync(sums, 0, 128 * sizeof(float), stream);

  node_transform_kernel<<<1024, 256, 0, stream>>>(feat, W, b, A, Bmh);
  degree_kernel<<<(N_EDGES + 255) / 256, 256, 0, stream>>>(ei, deg);
  scan1_kernel<<<NB_SCAN, 1024, 0, stream>>>(deg, pre, bsum);
  scan2_kernel<<<1, 128, 0, stream>>>(bsum, NB_SCAN);
  scan3_kernel<<<(N_NODES + 255) / 256, 256, 0, stream>>>(pre, bsum, row_ptr,
                                                          gcur);
  bucket_scatter_kernel<<<(N_EDGES + EPB - 1) / EPB, 256, 0, stream>>>(ei, gcur,
                                                                       pbuf);
  bucket_sort_kernel<<<NBUCK, 1024, 0, stream>>>(row_ptr, pbuf, esrc);
  stats_kernel<<<2048, 256, 0, stream>>>(row_ptr, esrc, A, Bmh, sums);
  bn_params_kernel<<<1, 64, 0, stream>>>(sums, gamma, beta, ss);
  aggregate_kernel<<<2048, 256, 0, stream>>>(row_ptr, esrc, A, Bmh, ss, out);
}

// Round 6
// 283.203 us; speedup vs baseline: 1.3862x; 1.3862x over previous
//
#include <hip/hip_runtime.h>

#define N_NODES 100000
#define N_EDGES 1600000
#define NBUCK 196   // ceil(N_NODES / 512)
#define EPB 4096    // edges per block in bucket_scatter
#define CAPB 9500   // LDS staging capacity in bucket_sort (mean 8192, sigma ~90)
#define NTILES 6250 // N_NODES / 16 (exact)

static constexpr float BN_EPS = 1e-5f;
static constexpr float SLOPE = 0.3f;

typedef __attribute__((ext_vector_type(8))) short bh8;   // 8 bf16 (4 VGPR)
typedef __attribute__((ext_vector_type(4))) float f32x4; // MFMA accum

__device__ __forceinline__ float bf16_to_f32(ushort u) {
  return __uint_as_float((unsigned)u << 16);
}
__device__ __forceinline__ ushort f32_to_bf16(float f) {
  unsigned bits = __float_as_uint(f);
  bits += 0x7FFFu + ((bits >> 16) & 1u);  // round-to-nearest-even
  return (ushort)(bits >> 16);
}

// ---------------------------------------------------------------------------
// Pass 0: feat fp32 -> bf16 (streaming, vectorized). 8 elems/thread.
// ---------------------------------------------------------------------------
__global__ __launch_bounds__(256) void feat_to_bf16_kernel(
    const float* __restrict__ feat, ushort* __restrict__ featH) {
  size_t i = (size_t)blockIdx.x * 256 + threadIdx.x;  // 800000 threads exact
  const float4* p = (const float4*)feat + i * 2;
  float4 a = p[0], b = p[1];
  uint4 o;
  o.x = (unsigned)f32_to_bf16(a.x) | ((unsigned)f32_to_bf16(a.y) << 16);
  o.y = (unsigned)f32_to_bf16(a.z) | ((unsigned)f32_to_bf16(a.w) << 16);
  o.z = (unsigned)f32_to_bf16(b.x) | ((unsigned)f32_to_bf16(b.y) << 16);
  o.w = (unsigned)f32_to_bf16(b.z) | ((unsigned)f32_to_bf16(b.w) << 16);
  ((uint4*)featH)[i] = o;
}

// ---------------------------------------------------------------------------
// Pass 1: node transforms via MFMA.  C[100000 x 128] = F[100000 x 64] @ Wt.
//   A_out[n][c] = feat[n] @ (W1-W2)^T[c] + b[c]   (fp32, in d_out)
//   B_out[n][c] = feat[n] @ W2^T[c]               (bf16 gather pool)
// Wave = 16-node tile. mfma_f32_16x16x32_bf16:
//   A-frag: lane l holds F[l&15][8*(l>>4)+i]   (row = node)
//   B-frag: lane l holds Wt[8*(l>>4)+i][l&15]  (col = channel)
//   D: col = lane&15, row = (lane>>4)*4 + reg  (m89-verified)
// Weight frags register-resident (built once per wave); bias in accum init.
// ---------------------------------------------------------------------------
__global__ __launch_bounds__(256) void node_transform_kernel(
    const ushort* __restrict__ featH, const float* __restrict__ W,
    const float* __restrict__ bias, float* __restrict__ A,
    ushort* __restrict__ Bmh) {
  int lane = threadIdx.x & 63;
  int cl = lane & 15;  // node-row for A-frag; channel-col for B-frag/D
  int q = lane >> 4;   // k-group

  // Prologue: build weight fragments.  Wa[k][c] = W[c*128+k] - W[c*128+64+k],
  // Wb[k][c] = W[c*128+64+k].  Lane needs k = 32s + 8q + i, c = 16ct + cl.
  bh8 wA[4][2], wB[4][2];
  float bv[4];
#pragma unroll
  for (int ct = 0; ct < 4; ++ct) {
    int c = ct * 16 + cl;
    bv[ct] = bias[c];
    const float* wr = W + (size_t)c * 128 + q * 8;
#pragma unroll
    for (int s = 0; s < 2; ++s) {
      const float* p = wr + 32 * s;
      float4 w1a = *(const float4*)(p);
      float4 w1b = *(const float4*)(p + 4);
      float4 w2a = *(const float4*)(p + 64);
      float4 w2b = *(const float4*)(p + 68);
      bh8 fa, fb;
      fa[0] = (short)f32_to_bf16(w1a.x - w2a.x); fb[0] = (short)f32_to_bf16(w2a.x);
      fa[1] = (short)f32_to_bf16(w1a.y - w2a.y); fb[1] = (short)f32_to_bf16(w2a.y);
      fa[2] = (short)f32_to_bf16(w1a.z - w2a.z); fb[2] = (short)f32_to_bf16(w2a.z);
      fa[3] = (short)f32_to_bf16(w1a.w - w2a.w); fb[3] = (short)f32_to_bf16(w2a.w);
      fa[4] = (short)f32_to_bf16(w1b.x - w2b.x); fb[4] = (short)f32_to_bf16(w2b.x);
      fa[5] = (short)f32_to_bf16(w1b.y - w2b.y); fb[5] = (short)f32_to_bf16(w2b.y);
      fa[6] = (short)f32_to_bf16(w1b.z - w2b.z); fb[6] = (short)f32_to_bf16(w2b.z);
      fa[7] = (short)f32_to_bf16(w1b.w - w2b.w); fb[7] = (short)f32_to_bf16(w2b.w);
      wA[ct][s] = fa;
      wB[ct][s] = fb;
    }
  }

  int gwave = blockIdx.x * 4 + (threadIdx.x >> 6);
  int nwaves = gridDim.x * 4;
  for (int tile = gwave; tile < NTILES; tile += nwaves) {
    int n0 = tile * 16;
    const ushort* fp = featH + (size_t)(n0 + cl) * 64 + q * 8;
    bh8 af0 = *(const bh8*)(fp);       // k = 8q+i
    bh8 af1 = *(const bh8*)(fp + 32);  // k = 32+8q+i
    f32x4 accA[4], accB[4];
#pragma unroll
    for (int ct = 0; ct < 4; ++ct) {
      accA[ct] = (f32x4){bv[ct], bv[ct], bv[ct], bv[ct]};
      accB[ct] = (f32x4){0.f, 0.f, 0.f, 0.f};
    }
#pragma unroll
    for (int ct = 0; ct < 4; ++ct) {
      accA[ct] = __builtin_amdgcn_mfma_f32_16x16x32_bf16(af0, wA[ct][0], accA[ct], 0, 0, 0);
      accA[ct] = __builtin_amdgcn_mfma_f32_16x16x32_bf16(af1, wA[ct][1], accA[ct], 0, 0, 0);
      accB[ct] = __builtin_amdgcn_mfma_f32_16x16x32_bf16(af0, wB[ct][0], accB[ct], 0, 0, 0);
      accB[ct] = __builtin_amdgcn_mfma_f32_16x16x32_bf16(af1, wB[ct][1], accB[ct], 0, 0, 0);
    }
    int rbase = n0 + 4 * q;
#pragma unroll
    for (int i = 0; i < 4; ++i) {
      size_t ro = (size_t)(rbase + i) * 64;
#pragma unroll
      for (int ct = 0; ct < 4; ++ct) {
        A[ro + ct * 16 + cl] = accA[ct][i];
        Bmh[ro + ct * 16 + cl] = f32_to_bf16(accB[ct][i]);
      }
    }
  }
}

// ---------------------------------------------------------------------------
// CSR build: degree histogram -> 3-dispatch parallel scan.
// ---------------------------------------------------------------------------
__global__ __launch_bounds__(256) void degree_kernel(const int* __restrict__ ei,
                                                     int* __restrict__ deg) {
  int e = blockIdx.x * 256 + threadIdx.x;
  if (e < N_EDGES) atomicAdd(&deg[ei[N_EDGES + e]], 1);  // dst
}

__global__ __launch_bounds__(1024) void scan1_kernel(const int* __restrict__ deg,
                                                     int* __restrict__ pre,
                                                     int* __restrict__ bsum) {
  __shared__ int sh[1024];
  int t = threadIdx.x;
  int i = blockIdx.x * 1024 + t;
  int v = (i < N_NODES) ? deg[i] : 0;
  sh[t] = v;
  __syncthreads();
  for (int off = 1; off < 1024; off <<= 1) {
    int u = (t >= off) ? sh[t - off] : 0;
    __syncthreads();
    sh[t] += u;
    __syncthreads();
  }
  if (i < N_NODES) pre[i] = sh[t] - v;  // exclusive within block
  if (t == 1023) bsum[blockIdx.x] = sh[1023];
}

__global__ __launch_bounds__(128) void scan2_kernel(int* __restrict__ bsum,
                                                    int nb) {
  __shared__ int sh[128];
  int t = threadIdx.x;
  int v = (t < nb) ? bsum[t] : 0;
  sh[t] = v;
  __syncthreads();
  for (int off = 1; off < 128; off <<= 1) {
    int u = (t >= off) ? sh[t - off] : 0;
    __syncthreads();
    sh[t] += u;
    __syncthreads();
  }
  if (t < nb) bsum[t] = sh[t] - v;  // exclusive
}

__global__ __launch_bounds__(256) void scan3_kernel(const int* __restrict__ pre,
                                                    const int* __restrict__ bsum,
                                                    int* __restrict__ row_ptr,
                                                    int* __restrict__ gcur) {
  int i = blockIdx.x * 256 + threadIdx.x;
  if (i < N_NODES) {
    int r = pre[i] + bsum[i >> 10];
    row_ptr[i] = r;
    if ((i & 511) == 0) gcur[i >> 9] = r;  // bucket base cursor
  }
  if (i == 0) row_ptr[N_NODES] = N_EDGES;
}

// ---------------------------------------------------------------------------
// B1: coarse bucket scatter (block-aggregated reservation, packed u32 runs).
// ---------------------------------------------------------------------------
__global__ __launch_bounds__(256) void bucket_scatter_kernel(
    const int* __restrict__ ei, int* __restrict__ gcur,
    unsigned* __restrict__ pbuf) {
  __shared__ int base[NBUCK];
  __shared__ int hist[NBUCK];
  int t = threadIdx.x;
  int e0 = blockIdx.x * EPB;
  int nE = min(EPB, N_EDGES - e0);

  for (int i = t; i < NBUCK; i += 256) hist[i] = 0;
  __syncthreads();
  for (int i = t; i < nE; i += 256) {
    int d = ei[N_EDGES + e0 + i];
    atomicAdd(&hist[d >> 9], 1);
  }
  __syncthreads();
  for (int i = t; i < NBUCK; i += 256) {
    int h = hist[i];
    base[i] = h ? atomicAdd(&gcur[i], h) : 0;
    hist[i] = 0;  // reuse as local cursor
  }
  __syncthreads();
  for (int i = t; i < nE; i += 256) {
    int d = ei[N_EDGES + e0 + i];
    int s = ei[e0 + i];
    int b = d >> 9;
    int off = atomicAdd(&hist[b], 1);
    pbuf[base[b] + off] = ((unsigned)(d & 511) << 17) | (unsigned)s;
  }
}

// ---------------------------------------------------------------------------
// B2: per-bucket fine sort via LDS staging.
// ---------------------------------------------------------------------------
__global__ __launch_bounds__(1024) void bucket_sort_kernel(
    const int* __restrict__ row_ptr, const unsigned* __restrict__ pbuf,
    int* __restrict__ esrc) {
  __shared__ int pref[512];
  __shared__ int cur[512];
  __shared__ int buf[CAPB];
  int t = threadIdx.x;
  int node0 = blockIdx.x << 9;
  int nn = min(512, N_NODES - node0);
  int fbase = row_ptr[node0];
  int fend = row_ptr[min(node0 + 512, N_NODES)];
  int m = fend - fbase;
  if (t < nn) {
    pref[t] = row_ptr[node0 + t] - fbase;
    cur[t] = 0;
  }
  __syncthreads();
  for (int i = t; i < m; i += 1024) {
    unsigned v = pbuf[fbase + i];
    int ldst = v >> 17;
    int src = (int)(v & 0x1FFFFu);
    int pos = pref[ldst] + atomicAdd(&cur[ldst], 1);
    if (pos < CAPB) buf[pos] = src;
    else esrc[fbase + pos] = src;  // overflow fallback (statistically never)
  }
  __syncthreads();
  int lim = min(m, CAPB);
  for (int i = t; i < lim; i += 1024) esrc[fbase + i] = buf[i];
}

// ---------------------------------------------------------------------------
// Pass 2: BN statistics, pull-based. bf16 gathers, 8-deep pipelined.
// ---------------------------------------------------------------------------
__global__ __launch_bounds__(256) void stats_kernel(
    const int* __restrict__ row_ptr, const int* __restrict__ esrc,
    const float* __restrict__ A, const ushort* __restrict__ Bmh,
    float* __restrict__ sums) {
  int lane = threadIdx.x & 63;
  int wv = threadIdx.x >> 6;
  int gwave = blockIdx.x * 4 + wv;
  int nwaves = gridDim.x * 4;

  float s = 0.f, sq = 0.f;
  for (int n = gwave; n < N_NODES; n += nwaves) {
    float a = A[n * 64 + lane];
    int lo = row_ptr[n], hi = row_ptr[n + 1];
    for (int base = lo; base < hi; base += 64) {
      int nb = min(64, hi - base);
      int sidx = (lane < nb) ? esrc[base + lane] : 0;  // coalesced
      int k = 0;
      for (; k + 8 <= nb; k += 8) {
        int i0 = __shfl(sidx, k + 0), i1 = __shfl(sidx, k + 1);
        int i2 = __shfl(sidx, k + 2), i3 = __shfl(sidx, k + 3);
        int i4 = __shfl(sidx, k + 4), i5 = __shfl(sidx, k + 5);
        int i6 = __shfl(sidx, k + 6), i7 = __shfl(sidx, k + 7);
        ushort u0 = Bmh[i0 * 64 + lane];  // 8 independent gathers in flight
        ushort u1 = Bmh[i1 * 64 + lane];
        ushort u2 = Bmh[i2 * 64 + lane];
        ushort u3 = Bmh[i3 * 64 + lane];
        ushort u4 = Bmh[i4 * 64 + lane];
        ushort u5 = Bmh[i5 * 64 + lane];
        ushort u6 = Bmh[i6 * 64 + lane];
        ushort u7 = Bmh[i7 * 64 + lane];
        float m0 = a + bf16_to_f32(u0), m1 = a + bf16_to_f32(u1);
        float m2 = a + bf16_to_f32(u2), m3 = a + bf16_to_f32(u3);
        float m4 = a + bf16_to_f32(u4), m5 = a + bf16_to_f32(u5);
        float m6 = a + bf16_to_f32(u6), m7 = a + bf16_to_f32(u7);
        s += ((m0 + m1) + (m2 + m3)) + ((m4 + m5) + (m6 + m7));
        sq = fmaf(m0, m0, sq); sq = fmaf(m1, m1, sq);
        sq = fmaf(m2, m2, sq); sq = fmaf(m3, m3, sq);
        sq = fmaf(m4, m4, sq); sq = fmaf(m5, m5, sq);
        sq = fmaf(m6, m6, sq); sq = fmaf(m7, m7, sq);
      }
      for (; k < nb; ++k) {
        int i0 = __shfl(sidx, k);
        float m = a + bf16_to_f32(Bmh[i0 * 64 + lane]);
        s += m;
        sq = fmaf(m, m, sq);
      }
    }
  }
  __shared__ float ls[4][64];
  __shared__ float lq[4][64];
  ls[wv][lane] = s;
  lq[wv][lane] = sq;
  __syncthreads();
  if (wv == 0) {
    atomicAdd(&sums[lane], ls[0][lane] + ls[1][lane] + ls[2][lane] + ls[3][lane]);
    atomicAdd(&sums[64 + lane],
              lq[0][lane] + lq[1][lane] + lq[2][lane] + lq[3][lane]);
  }
}

__global__ __launch_bounds__(64) void bn_params_kernel(
    const float* __restrict__ sums, const float* __restrict__ gamma,
    const float* __restrict__ beta, float* __restrict__ ss) {
  int c = threadIdx.x;
  const float invE = 1.0f / (float)N_EDGES;
  float mu = sums[c] * invE;
  float var = sums[64 + c] * invE - mu * mu;
  float rs = rsqrtf(var + BN_EPS);
  float sc = gamma[c] * rs;
  ss[c] = sc;
  ss[64 + c] = beta[c] - mu * sc;
}

// ---------------------------------------------------------------------------
// Pass 3: aggregation, pull-based, bf16 gathers, 8-deep pipelined.
// ---------------------------------------------------------------------------
__global__ __launch_bounds__(256) void aggregate_kernel(
    const int* __restrict__ row_ptr, const int* __restrict__ esrc,
    const float* __restrict__ A, const ushort* __restrict__ Bmh,
    const float* __restrict__ ss, float* __restrict__ out) {
  int lane = threadIdx.x & 63;
  int wv = threadIdx.x >> 6;
  int gwave = blockIdx.x * 4 + wv;
  int nwaves = gridDim.x * 4;

  float sc = ss[lane];
  float sh = ss[64 + lane];

  for (int n = gwave; n < N_NODES; n += nwaves) {
    float a = A[n * 64 + lane];  // A aliases out: read before write
    int lo = row_ptr[n], hi = row_ptr[n + 1];
    float acc = 0.f;
    for (int base = lo; base < hi; base += 64) {
      int nb = min(64, hi - base);
      int sidx = (lane < nb) ? esrc[base + lane] : 0;
      int k = 0;
      for (; k + 8 <= nb; k += 8) {
        int i0 = __shfl(sidx, k + 0), i1 = __shfl(sidx, k + 1);
        int i2 = __shfl(sidx, k + 2), i3 = __shfl(sidx, k + 3);
        int i4 = __shfl(sidx, k + 4), i5 = __shfl(sidx, k + 5);
        int i6 = __shfl(sidx, k + 6), i7 = __shfl(sidx, k + 7);
        ushort u0 = Bmh[i0 * 64 + lane];
        ushort u1 = Bmh[i1 * 64 + lane];
        ushort u2 = Bmh[i2 * 64 + lane];
        ushort u3 = Bmh[i3 * 64 + lane];
        ushort u4 = Bmh[i4 * 64 + lane];
        ushort u5 = Bmh[i5 * 64 + lane];
        ushort u6 = Bmh[i6 * 64 + lane];
        ushort u7 = Bmh[i7 * 64 + lane];
        float y0 = fmaf(a + bf16_to_f32(u0), sc, sh);
        float y1 = fmaf(a + bf16_to_f32(u1), sc, sh);
        float y2 = fmaf(a + bf16_to_f32(u2), sc, sh);
        float y3 = fmaf(a + bf16_to_f32(u3), sc, sh);
        float y4 = fmaf(a + bf16_to_f32(u4), sc, sh);
        float y5 = fmaf(a + bf16_to_f32(u5), sc, sh);
        float y6 = fmaf(a + bf16_to_f32(u6), sc, sh);
        float y7 = fmaf(a + bf16_to_f32(u7), sc, sh);
        y0 = (y0 >= 0.f) ? y0 : SLOPE * y0;
        y1 = (y1 >= 0.f) ? y1 : SLOPE * y1;
        y2 = (y2 >= 0.f) ? y2 : SLOPE * y2;
        y3 = (y3 >= 0.f) ? y3 : SLOPE * y3;
        y4 = (y4 >= 0.f) ? y4 : SLOPE * y4;
        y5 = (y5 >= 0.f) ? y5 : SLOPE * y5;
        y6 = (y6 >= 0.f) ? y6 : SLOPE * y6;
        y7 = (y7 >= 0.f) ? y7 : SLOPE * y7;
        acc += ((y0 + y1) + (y2 + y3)) + ((y4 + y5) + (y6 + y7));
      }
      for (; k < nb; ++k) {
        int i0 = __shfl(sidx, k);
        float y = fmaf(a + bf16_to_f32(Bmh[i0 * 64 + lane]), sc, sh);
        acc += (y >= 0.f) ? y : SLOPE * y;
      }
    }
    int cnt = hi - lo;
    out[n * 64 + lane] = acc * (1.0f / (float)max(cnt, 1));
  }
}

extern "C" void kernel_launch(void* const* d_in, const int* in_sizes, int n_in,
                              void* d_out, int out_size, void* d_ws,
                              size_t ws_size, hipStream_t stream) {
  const float* feat = (const float*)d_in[0];
  const int* ei = (const int*)d_in[1];
  const float* W = (const float*)d_in[2];
  const float* b = (const float*)d_in[3];
  const float* gamma = (const float*)d_in[4];
  const float* beta = (const float*)d_in[5];
  float* out = (float*)d_out;

  float* A = out;  // A lives in d_out; final pass overwrites in place

  // Workspace layout (~40 MB). featH first for 16B alignment.
  ushort* featH = (ushort*)d_ws;                       // N*64 bf16 (12.8 MB)
  ushort* Bmh = featH + (size_t)N_NODES * 64;          // N*64 bf16 (12.8 MB)
  float* sums = (float*)(Bmh + (size_t)N_NODES * 64);  // 128 f
  float* ss = sums + 128;                              // 128 f
  int* deg = (int*)(ss + 128);                         // N
  int* row_ptr = deg + N_NODES;                        // N+1
  int* pre = row_ptr + N_NODES + 1;                    // N
  int* bsum = pre + N_NODES;                           // 128
  int* gcur = bsum + 128;                              // NBUCK
  unsigned* pbuf = (unsigned*)(gcur + NBUCK);          // E packed
  int* esrc = (int*)(pbuf + N_EDGES);                  // E

  const int NB_SCAN = (N_NODES + 1023) / 1024;  // 98

  hipMemsetAsync(deg, 0, (size_t)N_NODES * sizeof(int), stream);
  hipMemsetAsync(sums, 0, 128 * sizeof(float), stream);

  feat_to_bf16_kernel<<<N_NODES * 64 / (256 * 8), 256, 0, stream>>>(feat, featH);
  node_transform_kernel<<<512, 256, 0, stream>>>(featH, W, b, A, Bmh);
  degree_kernel<<<(N_EDGES + 255) / 256, 256, 0, stream>>>(ei, deg);
  scan1_kernel<<<NB_SCAN, 1024, 0, stream>>>(deg, pre, bsum);
  scan2_kernel<<<1, 128, 0, stream>>>(bsum, NB_SCAN);
  scan3_kernel<<<(N_NODES + 255) / 256, 256, 0, stream>>>(pre, bsum, row_ptr,
                                                          gcur);
  bucket_scatter_kernel<<<(N_EDGES + EPB - 1) / EPB, 256, 0, stream>>>(ei, gcur,
                                                                       pbuf);
  bucket_sort_kernel<<<NBUCK, 1024, 0, stream>>>(row_ptr, pbuf, esrc);
  stats_kernel<<<2048, 256, 0, stream>>>(row_ptr, esrc, A, Bmh, sums);
  bn_params_kernel<<<1, 64, 0, stream>>>(sums, gamma, beta, ss);
  aggregate_kernel<<<2048, 256, 0, stream>>>(row_ptr, esrc, A, Bmh, ss, out);
}